// Round 5
// baseline (113.802 us; speedup 1.0000x reference)
//
#include <hip/hip_runtime.h>

// CensusLoss = mean |census(pred)-census(target)| = mismatch_count / (8*48*512*512).
// Fused kernel, 64x64 tile, 512 threads (8 px rows per thread, 1 column each).
// - Gray computed on the fly into column-major LDS halo [x][y], PITCH 76:
//   columns 16B-aligned -> window reads are b128/b64; lane stride 76 == 12 mod 32
//   -> b128 spans tile all 32 banks (conflict-free reads).
// - Interior-x blocks stage with float4 global loads (y-reflect is row-uniform,
//   never breaks vectorization); x-edge blocks use the scalar reflect path.
// - Wave-specialized pipeline: stage rows 0..37 | waves0-3 compute px rows 0..31
//   while waves4-7 stage rows 38..69 | waves4-7 compute. Overlaps ~half the
//   HBM staging with compute without compiler-scheduling reliance.

#define BATCH 8
#define HH 512
#define WW 512
#define PLANE (HH * WW)
#define TW 64
#define TH 64
#define SCOLS 72          // staged cols: gx = tx0-4+lx (extra col each side for f4 align)
#define HROWS 70          // halo rows:  gy = ty0-3+hy
#define S1 38             // stage-1 rows 0..37 (covers px rows 0..31)
#define S2 (HROWS - S1)   // 32
#define KPR 18            // float4 chunks per halo row (72/4)
#define PITCH 76          // column pitch: %4==0 (16B cols); 76 mod 32 = 12 (good b128 banking)
#define NT 512

__device__ __forceinline__ int refl(int v, int n) {
    return v < 0 ? -v : (v >= n ? 2 * n - 2 - v : v);
}

__global__ __launch_bounds__(NT, 4)
void census_fused(const float* __restrict__ pred,
                  const float* __restrict__ target,
                  float* __restrict__ out) {
    __shared__ __align__(16) float sP[SCOLS][PITCH];
    __shared__ __align__(16) float sT[SCOLS][PITCH];

    const int b   = blockIdx.z;
    const int ty0 = blockIdx.y * TH;
    const int tx0 = blockIdx.x * TW;
    const float* __restrict__ pb = pred   + (size_t)b * 3 * PLANE;
    const float* __restrict__ tb = target + (size_t)b * 3 * PLANE;
    const bool fastx = (blockIdx.x >= 1 && blockIdx.x <= 6);  // gx in-range -> float4 path

    auto stage_fast = [&](int hy, int k) {
        const int gy  = refl(ty0 + hy - 3, HH);
        const int off = gy * WW + tx0 - 4 + 4 * k;            // 16B-aligned
        const float4 pr = *(const float4*)(pb + off);
        const float4 pg = *(const float4*)(pb + off + PLANE);
        const float4 pc = *(const float4*)(pb + off + 2 * PLANE);
        const float4 tr = *(const float4*)(tb + off);
        const float4 tg = *(const float4*)(tb + off + PLANE);
        const float4 tc = *(const float4*)(tb + off + 2 * PLANE);
        const int lx = 4 * k;
        sP[lx + 0][hy] = 0.299f * pr.x + 0.587f * pg.x + 0.114f * pc.x;
        sP[lx + 1][hy] = 0.299f * pr.y + 0.587f * pg.y + 0.114f * pc.y;
        sP[lx + 2][hy] = 0.299f * pr.z + 0.587f * pg.z + 0.114f * pc.z;
        sP[lx + 3][hy] = 0.299f * pr.w + 0.587f * pg.w + 0.114f * pc.w;
        sT[lx + 0][hy] = 0.299f * tr.x + 0.587f * tg.x + 0.114f * tc.x;
        sT[lx + 1][hy] = 0.299f * tr.y + 0.587f * tg.y + 0.114f * tc.y;
        sT[lx + 2][hy] = 0.299f * tr.z + 0.587f * tg.z + 0.114f * tc.z;
        sT[lx + 3][hy] = 0.299f * tr.w + 0.587f * tg.w + 0.114f * tc.w;
    };
    auto stage_scalar = [&](int hy, int lx) {
        const int gy  = refl(ty0 + hy - 3, HH);
        const int gx  = refl(tx0 + lx - 4, WW);
        const int off = gy * WW + gx;
        sP[lx][hy] = 0.299f * pb[off] + 0.587f * pb[off + PLANE] + 0.114f * pb[off + 2 * PLANE];
        sT[lx][hy] = 0.299f * tb[off] + 0.587f * tb[off + PLANE] + 0.114f * tb[off + 2 * PLANE];
    };

    // ---- stage 1: halo rows 0..S1-1 (all 512 threads) ----
    if (fastx) {
        for (int idx = threadIdx.x; idx < S1 * KPR; idx += NT) {
            const int hy = idx / KPR;
            stage_fast(hy, idx - hy * KPR);
        }
    } else {
        for (int idx = threadIdx.x; idx < S1 * SCOLS; idx += NT) {
            const int hy = idx / SCOLS;
            stage_scalar(hy, idx - hy * SCOLS);
        }
    }
    __syncthreads();

    const int wv = threadIdx.x >> 6;   // wave == row band
    const int c  = threadIdx.x & 63;   // pixel column in tile

    // Window loads: halo col lx, rows pr0..pr0+13 as f4,f4,f4,f2 (16B-aligned).
    auto load_col = [&](const float* col, float* w) {
        *(float4*)&w[0]  = *(const float4*)(col);
        *(float4*)&w[4]  = *(const float4*)(col + 4);
        *(float4*)&w[8]  = *(const float4*)(col + 8);
        *(float2*)&w[12] = *(const float2*)(col + 12);
    };
    // Pixel (tx0+c, ty0+pr0+p), p=0..7: center at halo [c+4][pr0+3+p];
    // window cols lx = c+1..c+7, rows pr0..pr0+13.
    auto band_count = [&](int pr0) -> int {
        float wP[14], wT[14], cP[8], cT[8];
        int cnt = 0;
        load_col(&sP[c + 4][pr0], wP);          // dx = 0 column (holds centers)
        load_col(&sT[c + 4][pr0], wT);
        #pragma unroll
        for (int p = 0; p < 8; ++p) { cP[p] = wP[3 + p]; cT[p] = wT[3 + p]; }
        #pragma unroll
        for (int p = 0; p < 8; ++p) {
            #pragma unroll
            for (int dy = -3; dy <= 3; ++dy) {
                if (dy == 0) continue;          // skip center
                cnt += ((cP[p] > wP[3 + p + dy]) != (cT[p] > wT[3 + p + dy])) ? 1 : 0;
            }
        }
        #pragma unroll
        for (int t = 0; t < 6; ++t) {
            const int lx = c + 1 + (t < 3 ? t : t + 1);   // dx = -3..3, dx != 0
            load_col(&sP[lx][pr0], wP);
            load_col(&sT[lx][pr0], wT);
            #pragma unroll
            for (int p = 0; p < 8; ++p) {
                #pragma unroll
                for (int dy = -3; dy <= 3; ++dy)
                    cnt += ((cP[p] > wP[3 + p + dy]) != (cT[p] > wT[3 + p + dy])) ? 1 : 0;
            }
        }
        return cnt;
    };

    int cnt = 0;
    if (wv < 4) {
        // px rows 0..31: windows need halo rows 0..37 == stage 1. Compute now,
        // overlapped with waves 4..7 staging rows 38..69.
        cnt = band_count(wv * 8);
    } else {
        const int t2 = threadIdx.x - 256;
        if (fastx) {
            for (int idx = t2; idx < S2 * KPR; idx += 256) {
                const int r = idx / KPR;
                stage_fast(S1 + r, idx - r * KPR);
            }
        } else {
            for (int idx = t2; idx < S2 * SCOLS; idx += 256) {
                const int r = idx / SCOLS;
                stage_scalar(S1 + r, idx - r * SCOLS);
            }
        }
    }
    __syncthreads();
    if (wv >= 4) cnt = band_count(wv * 8);      // px rows 32..63 (halo rows 32..69)

    // Reduce: 64-lane shuffle, cross-wave LDS, one atomic per block.
    #pragma unroll
    for (int o = 32; o > 0; o >>= 1) cnt += __shfl_down(cnt, o, 64);
    __shared__ int wsum[8];
    if ((threadIdx.x & 63) == 0) wsum[wv] = cnt;
    __syncthreads();
    if (threadIdx.x == 0) {
        int tot = 0;
        #pragma unroll
        for (int w = 0; w < 8; ++w) tot += wsum[w];
        // N = 8 * 48 * 512 * 512 = 100663296
        atomicAdd(out, (float)tot * (1.0f / 100663296.0f));
    }
}

extern "C" void kernel_launch(void* const* d_in, const int* in_sizes, int n_in,
                              void* d_out, int out_size, void* d_ws, size_t ws_size,
                              hipStream_t stream) {
    const float* pred   = (const float*)d_in[0];
    const float* target = (const float*)d_in[1];
    float* out = (float*)d_out;

    hipMemsetAsync(out, 0, sizeof(float), stream);   // d_out poisoned 0xAA

    dim3 grid(WW / TW, HH / TH, BATCH);              // (8, 8, 8) = 512 blocks
    census_fused<<<grid, NT, 0, stream>>>(pred, target, out);
}